// Round 9
// baseline (227.169 us; speedup 1.0000x reference)
//
#include <hip/hip_runtime.h>
#include <stdint.h>

typedef _Float16 v8h __attribute__((ext_vector_type(8)));
typedef _Float16 v2h __attribute__((ext_vector_type(2)));
typedef float v4f __attribute__((ext_vector_type(4)));

#define NPTS 2048
#define BATCH 16
#define KNN 20
#define PAIRS (NPTS * KNN)   // 40960 per batch

// ---------- helpers ----------
__device__ __forceinline__ unsigned f2h2(float lo, float hi) {
  _Float16 a = (_Float16)lo, b = (_Float16)hi;   // RNE converts
  unsigned short ua, ub;
  __builtin_memcpy(&ua, &a, 2);
  __builtin_memcpy(&ub, &b, 2);
  return (unsigned)ua | ((unsigned)ub << 16);
}
// v_pk_add_f16 + v_pk_max_f16 via native _Float16 vectors (ROCm 7.2 header
// lacks a usable __hmax2 overload — R6 compile fail)
__device__ __forceinline__ unsigned hadd_relu(unsigned a, unsigned b) {
  v2h x, y;
  __builtin_memcpy(&x, &a, 4);
  __builtin_memcpy(&y, &b, 4);
  v2h r = x + y;
  v2h z = {(_Float16)0, (_Float16)0};
  r = __builtin_elementwise_max(r, z);
  unsigned o;
  __builtin_memcpy(&o, &r, 4);
  return o;
}
__device__ __forceinline__ v8h pack_a(uint4 P, uint4 Q) {
  uint4 R;
  R.x = hadd_relu(P.x, Q.x);
  R.y = hadd_relu(P.y, Q.y);
  R.z = hadd_relu(P.z, Q.z);
  R.w = hadd_relu(P.w, Q.w);
  v8h a;
  __builtin_memcpy(&a, &R, 16);
  return a;
}

// ---------- K0: fold M2a=W2*W1a, M2b=W2*(W1b-W1a); W3->fp16; zero H ----------
__global__ void prep_kernel(const float* __restrict__ W1, const float* __restrict__ W2,
                            const float* __restrict__ W3,
                            float* __restrict__ M2a, float* __restrict__ M2b,
                            unsigned short* __restrict__ W3h, int* __restrict__ H) {
  int g = blockIdx.x * 128 + threadIdx.x;      // 0..4095
  if (blockIdx.x == 0 && threadIdx.x < 128) {
    int o = threadIdx.x;
    float a0 = 0, a1 = 0, a2 = 0, b0 = 0, b1 = 0, b2 = 0;
    for (int i = 0; i < 64; ++i) {
      float w2 = W2[o * 64 + i];
      const float* w1r = W1 + i * 6;
      a0 += w2 * w1r[0]; a1 += w2 * w1r[1]; a2 += w2 * w1r[2];
      b0 += w2 * (w1r[3] - w1r[0]); b1 += w2 * (w1r[4] - w1r[1]); b2 += w2 * (w1r[5] - w1r[2]);
    }
    M2a[o * 3 + 0] = a0; M2a[o * 3 + 1] = a1; M2a[o * 3 + 2] = a2;
    M2b[o * 3 + 0] = b0; M2b[o * 3 + 1] = b1; M2b[o * 3 + 2] = b2;
  }
  // W3 (256x128 fp32) -> fp16 (RNE)
  for (int i = g; i < 256 * 128; i += 4096) {
    _Float16 h = (_Float16)W3[i];
    unsigned short u;
    __builtin_memcpy(&u, &h, 2);
    W3h[i] = u;
  }
  if (g < BATCH * 256) H[g] = 0;
}

// ---------- K1: p/q per point, fp16 packed pairs ----------
__global__ __launch_bounds__(64) void pq_kernel(const float* __restrict__ x,
                                                const float* __restrict__ M2a,
                                                const float* __restrict__ M2b,
                                                unsigned short* __restrict__ p,
                                                unsigned short* __restrict__ q) {
  int b = blockIdx.x >> 6;
  int j0 = (blockIdx.x & 63) << 5;
  int t = threadIdx.x;                 // 0..63 -> channels 2t, 2t+1
  int o0 = t * 2;
  float a00 = M2a[o0 * 3 + 0], a01 = M2a[o0 * 3 + 1], a02 = M2a[o0 * 3 + 2];
  float a10 = M2a[o0 * 3 + 3], a11 = M2a[o0 * 3 + 4], a12 = M2a[o0 * 3 + 5];
  float b00 = M2b[o0 * 3 + 0], b01 = M2b[o0 * 3 + 1], b02 = M2b[o0 * 3 + 2];
  float b10 = M2b[o0 * 3 + 3], b11 = M2b[o0 * 3 + 4], b12 = M2b[o0 * 3 + 5];
  const float* xb = x + b * 3 * NPTS;
  unsigned* pw = (unsigned*)p;
  unsigned* qw = (unsigned*)q;
  for (int jj = 0; jj < 32; ++jj) {
    int j = j0 + jj;
    float x0 = xb[j], x1 = xb[NPTS + j], x2 = xb[2 * NPTS + j];
    float p0 = a00 * x0 + a01 * x1 + a02 * x2;
    float p1 = a10 * x0 + a11 * x1 + a12 * x2;
    float q0 = b00 * x0 + b01 * x1 + b02 * x2;
    float q1 = b10 * x0 + b11 * x1 + b12 * x2;
    size_t base = ((size_t)(b * NPTS + j)) * 64 + t;   // dword index (128 fp16/row)
    pw[base] = f2h2(p0, p1);
    qw[base] = f2h2(q0, q1);
  }
}

// ---------- K2: exact 20-NN, 4 queries per wave (unchanged, passed R5) ----------
__global__ __launch_bounds__(256) void knn_kernel(const float* __restrict__ x,
                                                  int* __restrict__ idxOut) {
  __shared__ float px[NPTS], py[NPTS], pz[NPTS];      // 24 KB, stride-4B: conflict-free
  __shared__ unsigned long long cand[4][4][128];      // 16 KB, wave-private
  int b = blockIdx.x >> 7;
  int qblk = blockIdx.x & 127;
  const float* xb = x + b * 3 * NPTS;
  for (int i = threadIdx.x; i < NPTS; i += 256) {
    px[i] = xb[i]; py[i] = xb[NPTS + i]; pz[i] = xb[2 * NPTS + i];
  }
  __syncthreads();
  int wid = threadIdx.x >> 6, lane = threadIdx.x & 63;
  int qbase = qblk * 16 + wid * 4;                    // 4 queries per wave

  float qx[4], qy[4], qz[4], mn[4];
#pragma unroll
  for (int g = 0; g < 4; ++g) {
    qx[g] = px[qbase + g]; qy[g] = py[qbase + g]; qz[g] = pz[qbase + g];
    mn[g] = 1e30f;
  }

  for (int s = 0; s < 32; ++s) {
    int i = s * 64 + lane;
    float X = px[i], Y = py[i], Z = pz[i];
#pragma unroll
    for (int g = 0; g < 4; ++g) {
      float dx = X - qx[g], dy = Y - qy[g], dz = Z - qz[g];
      mn[g] = fminf(mn[g], dx * dx + dy * dy + dz * dz);
    }
  }

  float tau[4];
#pragma unroll
  for (int g = 0; g < 4; ++g) {
    float v = mn[g];
    for (int k = 2; k <= 64; k <<= 1) {
      for (int j = k >> 1; j > 0; j >>= 1) {
        float o = __shfl_xor(v, j);
        bool low = (lane & j) == 0;
        bool up = (lane & k) == 0;
        v = (low == up) ? fminf(v, o) : fmaxf(v, o);
      }
    }
    tau[g] = __shfl(v, 19) * (1.0f + 3.8e-6f);  // +2^-18: cross-pass FMA-contraction ulps
  }

  int cnt[4] = {0, 0, 0, 0};
  for (int s = 0; s < 32; ++s) {
    int i = s * 64 + lane;
    float X = px[i], Y = py[i], Z = pz[i];
#pragma unroll
    for (int g = 0; g < 4; ++g) {
      float dx = X - qx[g], dy = Y - qy[g], dz = Z - qz[g];
      float d = dx * dx + dy * dy + dz * dz;
      bool take = d <= tau[g];
      unsigned long long mb = __ballot(take);
      if (take) {
        int pos = cnt[g] + __popcll(mb & ((1ull << lane) - 1ull));
        if (pos < 128)
          cand[wid][g][pos] =
              (((unsigned long long)__float_as_uint(d)) << 32) | (unsigned)i;
      }
      cnt[g] += __popcll(mb);
    }
  }
  // cand is wave-private: no barrier needed.
#pragma unroll
  for (int g = 0; g < 4; ++g) {
    int nc = cnt[g] < 128 ? cnt[g] : 128;
    unsigned long long k0 = (lane < nc) ? cand[wid][g][lane] : ~0ull;
    unsigned long long k1 = (lane + 64 < nc) ? cand[wid][g][lane + 64] : ~0ull;
    int r0 = 0, r1 = 0;
    for (int i = 0; i < nc; ++i) {
      unsigned long long ki = cand[wid][g][i];
      r0 += (ki < k0) ? 1 : 0;
      r1 += (ki < k1) ? 1 : 0;
    }
    long long obase = ((long long)b * NPTS + qbase + g) * KNN;
    if (lane < nc && r0 < KNN) idxOut[obase + r0] = (int)(k0 & 0xffffffffu);
    if (lane + 64 < nc && r1 < KNN) idxOut[obase + r1] = (int)(k1 & 0xffffffffu);
  }
}

// ---------- K3: h3 = relu(W3 · relu(p_j+q_n)) via fp16 MFMA, fused max ----------
// R8 FAIL post-mortem: NOT the gemm — workspace overlap (p is 8.39 MB, not
// 4.19; q at +4.19 MB clobbered batches 8-15). R9: fix offsets only.
// LDS-FREE gemm: lane (r16,quad) gathers exactly its A-fragment bytes, 16B
// at row (tile*16+r16), offset kk*64+quad*16 — no LDS, no barriers, no bank
// conflicts. All 4 waves walk the SAME tiles (wid selects output channels).
__global__ __launch_bounds__(256, 3) void gemm_max_kernel(
    const unsigned short* __restrict__ p, const unsigned short* __restrict__ q,
    const int* __restrict__ idx, const unsigned short* __restrict__ W3h,
    int* __restrict__ H) {
  int b = blockIdx.x & 15;   // low bits = batch -> b%8 pins batch to XCD
  int w = blockIdx.x >> 4;   // 0..47 tile-chunk id (shared by all 4 waves)
  int t = threadIdx.x;
  int lane = t & 63, wid = t >> 6;
  int r16 = lane & 15, quad = lane >> 4;

  // B fragments: this wave's 64 output channels, fp16 pre-converted
  v8h bfr[4][4];
#pragma unroll
  for (int ntl = 0; ntl < 4; ++ntl) {
#pragma unroll
    for (int kk = 0; kk < 4; ++kk) {
      int n = (wid * 4 + ntl) * 16 + r16;
      bfr[ntl][kk] = *(const v8h*)(W3h + n * 128 + kk * 32 + quad * 8);
    }
  }

  const char* pB = (const char*)p + (size_t)b * NPTS * 256;
  const char* qB = (const char*)q + (size_t)b * NPTS * 256;
  const int* idxB = idx + (size_t)b * PAIRS;

  // 2560 tiles over 48 blocks: first 16 blocks get 54, rest 53
  int start = w * 53 + (w < 16 ? w : 16);
  int cnt = 53 + (w < 16 ? 1 : 0);

  // depth-1 prefetch of this lane's A-fragment bytes (pair row tile*16+r16)
  uint4 P4[4], Q4[4];
  {
    int pr = start * 16 + r16;
    int j = idxB[pr] & (NPTS - 1);
    unsigned n = (unsigned)pr / 20u;
    const char* prow = pB + (size_t)j * 256 + quad * 16;
    const char* qrow = qB + (size_t)n * 256 + quad * 16;
#pragma unroll
    for (int kk = 0; kk < 4; ++kk) {
      P4[kk] = *(const uint4*)(prow + kk * 64);
      Q4[kk] = *(const uint4*)(qrow + kk * 64);
    }
  }

  float vmx[4] = {0.f, 0.f, 0.f, 0.f};
  for (int i = 0; i < cnt; ++i) {
    // pack A fragments (consumes P4/Q4 -> regs free for next prefetch)
    v8h a[4];
#pragma unroll
    for (int kk = 0; kk < 4; ++kk) a[kk] = pack_a(P4[kk], Q4[kk]);

    // issue next tile's gathers; latency hidden behind the 16 MFMAs below
    if (i + 1 < cnt) {
      int pr = (start + i + 1) * 16 + r16;
      int j = idxB[pr] & (NPTS - 1);
      unsigned n = (unsigned)pr / 20u;
      const char* prow = pB + (size_t)j * 256 + quad * 16;
      const char* qrow = qB + (size_t)n * 256 + quad * 16;
#pragma unroll
      for (int kk = 0; kk < 4; ++kk) {
        P4[kk] = *(const uint4*)(prow + kk * 64);
        Q4[kk] = *(const uint4*)(qrow + kk * 64);
      }
    }

#pragma unroll
    for (int ntl = 0; ntl < 4; ++ntl) {
      v4f acc = {0.f, 0.f, 0.f, 0.f};
#pragma unroll
      for (int kk = 0; kk < 4; ++kk)
        acc = __builtin_amdgcn_mfma_f32_16x16x32_f16(a[kk], bfr[ntl][kk], acc, 0, 0, 0);
      // relu folds into max (vmx starts at 0); acc rows = pairs, col = channel
      vmx[ntl] = fmaxf(vmx[ntl], fmaxf(fmaxf(acc[0], acc[1]), fmaxf(acc[2], acc[3])));
    }
  }

  // rows are pairs -> max across quads, then device atomicMax per channel
#pragma unroll
  for (int ntl = 0; ntl < 4; ++ntl) {
    float vv = vmx[ntl];
    vv = fmaxf(vv, __shfl_xor(vv, 16));
    vv = fmaxf(vv, __shfl_xor(vv, 32));
    if (quad == 0) {
      int ch = (wid * 4 + ntl) * 16 + r16;
      atomicMax(&H[b * 256 + ch], __float_as_int(vv));  // vv>=0: int order == float order
    }
  }
}

// ---------- K4: out = H @ fc_w^T + fc_b (one wave per output element) ----------
__global__ __launch_bounds__(64) void fc_kernel(const int* __restrict__ Hi,
                                                const float* __restrict__ fcw,
                                                const float* __restrict__ fcb,
                                                float* __restrict__ out) {
  int b = blockIdx.x / 10, r = blockIdx.x % 10;
  int lane = threadIdx.x;
  const float* Hb = (const float*)Hi + b * 256;
  float s = 0.f;
#pragma unroll
  for (int c = lane; c < 256; c += 64) s += Hb[c] * fcw[r * 256 + c];
#pragma unroll
  for (int m = 32; m > 0; m >>= 1) s += __shfl_xor(s, m);
  if (lane == 0) out[b * 10 + r] = s + fcb[r];
}

// ---------- launch ----------
extern "C" void kernel_launch(void* const* d_in, const int* in_sizes, int n_in,
                              void* d_out, int out_size, void* d_ws, size_t ws_size,
                              hipStream_t stream) {
  const float* x   = (const float*)d_in[0];
  const float* W1  = (const float*)d_in[1];
  const float* W2  = (const float*)d_in[2];
  const float* W3  = (const float*)d_in[3];
  const float* fcw = (const float*)d_in[4];
  const float* fcb = (const float*)d_in[5];
  float* out = (float*)d_out;
  char* ws = (char*)d_ws;

  // workspace layout — p and q are 16*2048*128*2 B = 8,388,608 B EACH
  // (R6-R8 bug: q placed at p+4.19MB overlapped p's upper half -> batches
  // 8-15 corrupted). Total ends at 19,488,768 < 20MB (proven available R1-R5).
  float* M2a = (float*)(ws + 0);                          // 1536 B
  float* M2b = (float*)(ws + 2048);                       // 1536 B
  int* H     = (int*)(ws + 8192);                         // 16 KB
  int* idx   = (int*)(ws + 24576);                        // 2,621,440 B
  unsigned short* W3h = (unsigned short*)(ws + 2646016);  // 65,536 B
  unsigned short* p   = (unsigned short*)(ws + 2711552);  // 8,388,608 B
  unsigned short* q   = (unsigned short*)(ws + 11100160); // 8,388,608 B

  prep_kernel<<<32, 128, 0, stream>>>(W1, W2, W3, M2a, M2b, W3h, H);
  pq_kernel<<<BATCH * 64, 64, 0, stream>>>(x, M2a, M2b, p, q);
  knn_kernel<<<BATCH * 128, 256, 0, stream>>>(x, idx);
  gemm_max_kernel<<<BATCH * 48, 256, 0, stream>>>(p, q, idx, W3h, H);
  fc_kernel<<<BATCH * 10, 64, 0, stream>>>(H, fcw, fcb, out);
}

// Round 10
// 192.977 us; speedup vs baseline: 1.1772x; 1.1772x over previous
//
#include <hip/hip_runtime.h>
#include <stdint.h>

typedef _Float16 v8h __attribute__((ext_vector_type(8)));
typedef _Float16 v2h __attribute__((ext_vector_type(2)));
typedef float v4f __attribute__((ext_vector_type(4)));

#define NPTS 2048
#define BATCH 16
#define KNN 20
#define PAIRS (NPTS * KNN)   // 40960 per batch

// ---------- helpers ----------
__device__ __forceinline__ unsigned f2h2(float lo, float hi) {
  _Float16 a = (_Float16)lo, b = (_Float16)hi;   // RNE converts
  unsigned short ua, ub;
  __builtin_memcpy(&ua, &a, 2);
  __builtin_memcpy(&ub, &b, 2);
  return (unsigned)ua | ((unsigned)ub << 16);
}
// v_pk_add_f16 + v_pk_max_f16 via native _Float16 vectors (ROCm 7.2 header
// lacks a usable __hmax2 overload — R6 compile fail)
__device__ __forceinline__ unsigned hadd_relu(unsigned a, unsigned b) {
  v2h x, y;
  __builtin_memcpy(&x, &a, 4);
  __builtin_memcpy(&y, &b, 4);
  v2h r = x + y;
  v2h z = {(_Float16)0, (_Float16)0};
  r = __builtin_elementwise_max(r, z);
  unsigned o;
  __builtin_memcpy(&o, &r, 4);
  return o;
}
__device__ __forceinline__ uint4 hadd_relu4(uint4 P, uint4 Q) {
  uint4 R;
  R.x = hadd_relu(P.x, Q.x);
  R.y = hadd_relu(P.y, Q.y);
  R.z = hadd_relu(P.z, Q.z);
  R.w = hadd_relu(P.w, Q.w);
  return R;
}

// ---------- K0: fold M2a=W2*W1a, M2b=W2*(W1b-W1a); W3->fp16; zero H ----------
__global__ void prep_kernel(const float* __restrict__ W1, const float* __restrict__ W2,
                            const float* __restrict__ W3,
                            float* __restrict__ M2a, float* __restrict__ M2b,
                            unsigned short* __restrict__ W3h, int* __restrict__ H) {
  int g = blockIdx.x * 128 + threadIdx.x;      // 0..4095
  if (blockIdx.x == 0 && threadIdx.x < 128) {
    int o = threadIdx.x;
    float a0 = 0, a1 = 0, a2 = 0, b0 = 0, b1 = 0, b2 = 0;
    for (int i = 0; i < 64; ++i) {
      float w2 = W2[o * 64 + i];
      const float* w1r = W1 + i * 6;
      a0 += w2 * w1r[0]; a1 += w2 * w1r[1]; a2 += w2 * w1r[2];
      b0 += w2 * (w1r[3] - w1r[0]); b1 += w2 * (w1r[4] - w1r[1]); b2 += w2 * (w1r[5] - w1r[2]);
    }
    M2a[o * 3 + 0] = a0; M2a[o * 3 + 1] = a1; M2a[o * 3 + 2] = a2;
    M2b[o * 3 + 0] = b0; M2b[o * 3 + 1] = b1; M2b[o * 3 + 2] = b2;
  }
  // W3 (256x128 fp32) -> fp16 (RNE)
  for (int i = g; i < 256 * 128; i += 4096) {
    _Float16 h = (_Float16)W3[i];
    unsigned short u;
    __builtin_memcpy(&u, &h, 2);
    W3h[i] = u;
  }
  if (g < BATCH * 256) H[g] = 0;
}

// ---------- K1: p/q per point, fp16 packed pairs ----------
__global__ __launch_bounds__(64) void pq_kernel(const float* __restrict__ x,
                                                const float* __restrict__ M2a,
                                                const float* __restrict__ M2b,
                                                unsigned short* __restrict__ p,
                                                unsigned short* __restrict__ q) {
  int b = blockIdx.x >> 6;
  int j0 = (blockIdx.x & 63) << 5;
  int t = threadIdx.x;                 // 0..63 -> channels 2t, 2t+1
  int o0 = t * 2;
  float a00 = M2a[o0 * 3 + 0], a01 = M2a[o0 * 3 + 1], a02 = M2a[o0 * 3 + 2];
  float a10 = M2a[o0 * 3 + 3], a11 = M2a[o0 * 3 + 4], a12 = M2a[o0 * 3 + 5];
  float b00 = M2b[o0 * 3 + 0], b01 = M2b[o0 * 3 + 1], b02 = M2b[o0 * 3 + 2];
  float b10 = M2b[o0 * 3 + 3], b11 = M2b[o0 * 3 + 4], b12 = M2b[o0 * 3 + 5];
  const float* xb = x + b * 3 * NPTS;
  unsigned* pw = (unsigned*)p;
  unsigned* qw = (unsigned*)q;
  for (int jj = 0; jj < 32; ++jj) {
    int j = j0 + jj;
    float x0 = xb[j], x1 = xb[NPTS + j], x2 = xb[2 * NPTS + j];
    float p0 = a00 * x0 + a01 * x1 + a02 * x2;
    float p1 = a10 * x0 + a11 * x1 + a12 * x2;
    float q0 = b00 * x0 + b01 * x1 + b02 * x2;
    float q1 = b10 * x0 + b11 * x1 + b12 * x2;
    size_t base = ((size_t)(b * NPTS + j)) * 64 + t;   // dword index (128 fp16/row)
    pw[base] = f2h2(p0, p1);
    qw[base] = f2h2(q0, q1);
  }
}

// ---------- K2: exact 20-NN, 4 queries per wave (unchanged, passed R5) ----------
__global__ __launch_bounds__(256) void knn_kernel(const float* __restrict__ x,
                                                  int* __restrict__ idxOut) {
  __shared__ float px[NPTS], py[NPTS], pz[NPTS];      // 24 KB, stride-4B: conflict-free
  __shared__ unsigned long long cand[4][4][128];      // 16 KB, wave-private
  int b = blockIdx.x >> 7;
  int qblk = blockIdx.x & 127;
  const float* xb = x + b * 3 * NPTS;
  for (int i = threadIdx.x; i < NPTS; i += 256) {
    px[i] = xb[i]; py[i] = xb[NPTS + i]; pz[i] = xb[2 * NPTS + i];
  }
  __syncthreads();
  int wid = threadIdx.x >> 6, lane = threadIdx.x & 63;
  int qbase = qblk * 16 + wid * 4;                    // 4 queries per wave

  float qx[4], qy[4], qz[4], mn[4];
#pragma unroll
  for (int g = 0; g < 4; ++g) {
    qx[g] = px[qbase + g]; qy[g] = py[qbase + g]; qz[g] = pz[qbase + g];
    mn[g] = 1e30f;
  }

  for (int s = 0; s < 32; ++s) {
    int i = s * 64 + lane;
    float X = px[i], Y = py[i], Z = pz[i];
#pragma unroll
    for (int g = 0; g < 4; ++g) {
      float dx = X - qx[g], dy = Y - qy[g], dz = Z - qz[g];
      mn[g] = fminf(mn[g], dx * dx + dy * dy + dz * dz);
    }
  }

  float tau[4];
#pragma unroll
  for (int g = 0; g < 4; ++g) {
    float v = mn[g];
    for (int k = 2; k <= 64; k <<= 1) {
      for (int j = k >> 1; j > 0; j >>= 1) {
        float o = __shfl_xor(v, j);
        bool low = (lane & j) == 0;
        bool up = (lane & k) == 0;
        v = (low == up) ? fminf(v, o) : fmaxf(v, o);
      }
    }
    tau[g] = __shfl(v, 19) * (1.0f + 3.8e-6f);  // +2^-18: cross-pass FMA-contraction ulps
  }

  int cnt[4] = {0, 0, 0, 0};
  for (int s = 0; s < 32; ++s) {
    int i = s * 64 + lane;
    float X = px[i], Y = py[i], Z = pz[i];
#pragma unroll
    for (int g = 0; g < 4; ++g) {
      float dx = X - qx[g], dy = Y - qy[g], dz = Z - qz[g];
      float d = dx * dx + dy * dy + dz * dz;
      bool take = d <= tau[g];
      unsigned long long mb = __ballot(take);
      if (take) {
        int pos = cnt[g] + __popcll(mb & ((1ull << lane) - 1ull));
        if (pos < 128)
          cand[wid][g][pos] =
              (((unsigned long long)__float_as_uint(d)) << 32) | (unsigned)i;
      }
      cnt[g] += __popcll(mb);
    }
  }
  // cand is wave-private: no barrier needed.
#pragma unroll
  for (int g = 0; g < 4; ++g) {
    int nc = cnt[g] < 128 ? cnt[g] : 128;
    unsigned long long k0 = (lane < nc) ? cand[wid][g][lane] : ~0ull;
    unsigned long long k1 = (lane + 64 < nc) ? cand[wid][g][lane + 64] : ~0ull;
    int r0 = 0, r1 = 0;
    for (int i = 0; i < nc; ++i) {
      unsigned long long ki = cand[wid][g][i];
      r0 += (ki < k0) ? 1 : 0;
      r1 += (ki < k1) ? 1 : 0;
    }
    long long obase = ((long long)b * NPTS + qbase + g) * KNN;
    if (lane < nc && r0 < KNN) idxOut[obase + r0] = (int)(k0 & 0xffffffffu);
    if (lane + 64 < nc && r1 < KNN) idxOut[obase + r1] = (int)(k1 & 0xffffffffu);
  }
}

// ---------- K3: h3 = relu(W3 · relu(p_j+q_n)) via fp16 MFMA, fused max ----------
// R9 post-mortem: direct A-fragment gather is address-DIVERGENT (64 distinct
// 64B chunks per instr; 2048 line-touches/tile) -> TA-throughput-bound 106us.
// R10: coalesced per-wave staging, zero barriers. Lane (rr=lane>>2, ss=lane&3)
// loads 16B at row-chunk c*64+ss*16 (consecutive lanes -> consecutive 64B;
// 16 chunks/instr). Pack fp16, transpose via WAVE-PRIVATE LDS quarter (272B
// row pad: rows stride 4 banks -> 2-way = free), ds_read A-frags, MFMA.
// Same-wave LDS write->read: lgkmcnt only, NO __syncthreads -> no convoy.
// Idx prefetched one tile beyond data so idx->gather chain never stalls.
__global__ __launch_bounds__(256, 3) void gemm_max_kernel(
    const unsigned short* __restrict__ p, const unsigned short* __restrict__ q,
    const int* __restrict__ idx, const unsigned short* __restrict__ W3h,
    int* __restrict__ H) {
  __shared__ __align__(16) char h2s[4][16 * 272];   // 17408 B, one tile per wave

  int b = blockIdx.x & 15;   // low bits = batch -> b%8 pins batch to XCD
  int c = blockIdx.x >> 4;   // 0..95 tile-chunk id (shared by all 4 waves)
  int t = threadIdx.x;
  int lane = t & 63, wid = t >> 6;
  int r16 = lane & 15, quad = lane >> 4;
  int rr = lane >> 2, ss = lane & 3;   // staging: pair-row 0..15, 64B-seg 0..3
  char* myT = h2s[wid];

  // B fragments: this wave's 64 output channels, fp16 pre-converted
  v8h bfr[4][4];
#pragma unroll
  for (int ntl = 0; ntl < 4; ++ntl) {
#pragma unroll
    for (int kk = 0; kk < 4; ++kk) {
      int n = (wid * 4 + ntl) * 16 + r16;
      bfr[ntl][kk] = *(const v8h*)(W3h + n * 128 + kk * 32 + quad * 8);
    }
  }

  const char* pB = (const char*)p + (size_t)b * NPTS * 256;
  const char* qB = (const char*)q + (size_t)b * NPTS * 256;
  const int* idxB = idx + (size_t)b * PAIRS;

  // 2560 tiles over 96 chunks: chunks 0..63 get 27, 64..95 get 26
  int start = c * 26 + (c < 64 ? c : 64);
  int cnt = 26 + (c < 64 ? 1 : 0);

  // first tile: idx -> gather (one cold stall)
  int jv = idxB[start * 16 + rr] & (NPTS - 1);
  uint4 P4[4], Q4[4];
  {
    unsigned nv = (unsigned)(start * 16 + rr) / 20u;
    const char* prow = pB + (size_t)jv * 256 + ss * 16;
    const char* qrow = qB + (size_t)nv * 256 + ss * 16;
#pragma unroll
    for (int cc = 0; cc < 4; ++cc) {
      P4[cc] = *(const uint4*)(prow + cc * 64);
      Q4[cc] = *(const uint4*)(qrow + cc * 64);
    }
  }
  // idx for tile start+1, consumed next iteration
  int jv_nxt = (cnt > 1) ? idxB[(start + 1) * 16 + rr] : 0;

  float vmx[4] = {0.f, 0.f, 0.f, 0.f};
  for (int i = 0; i < cnt; ++i) {
    // pack current tile (waits on this tile's gathers)
    uint4 R[4];
#pragma unroll
    for (int cc = 0; cc < 4; ++cc) R[cc] = hadd_relu4(P4[cc], Q4[cc]);

    // issue next tile's gathers (jv_nxt loaded a full iteration ago)
    if (i + 1 < cnt) {
      int tl = start + i + 1;
      int j = jv_nxt & (NPTS - 1);
      unsigned nv = (unsigned)(tl * 16 + rr) / 20u;
      const char* prow = pB + (size_t)j * 256 + ss * 16;
      const char* qrow = qB + (size_t)nv * 256 + ss * 16;
#pragma unroll
      for (int cc = 0; cc < 4; ++cc) {
        P4[cc] = *(const uint4*)(prow + cc * 64);
        Q4[cc] = *(const uint4*)(qrow + cc * 64);
      }
      // idx for tile i+2 (two tiles of latency cover)
      if (i + 2 < cnt) jv_nxt = idxB[(tl + 1) * 16 + rr];
    }

    // stage to wave-private LDS (coalesced, conflict-free)
#pragma unroll
    for (int cc = 0; cc < 4; ++cc)
      *(uint4*)(myT + rr * 272 + cc * 64 + ss * 16) = R[cc];

    // A fragments: A[m=r16][k=quad*8+j], bytes kk*64+quad*16 of row r16
    v8h a[4];
#pragma unroll
    for (int kk = 0; kk < 4; ++kk)
      a[kk] = *(const v8h*)(myT + r16 * 272 + kk * 64 + quad * 16);

#pragma unroll
    for (int ntl = 0; ntl < 4; ++ntl) {
      v4f acc = {0.f, 0.f, 0.f, 0.f};
#pragma unroll
      for (int kk = 0; kk < 4; ++kk)
        acc = __builtin_amdgcn_mfma_f32_16x16x32_f16(a[kk], bfr[ntl][kk], acc, 0, 0, 0);
      // relu folds into max (vmx starts at 0); acc rows = pairs, col = channel
      vmx[ntl] = fmaxf(vmx[ntl], fmaxf(fmaxf(acc[0], acc[1]), fmaxf(acc[2], acc[3])));
    }
  }

  // rows are pairs -> max across quads, then device atomicMax per channel
#pragma unroll
  for (int ntl = 0; ntl < 4; ++ntl) {
    float vv = vmx[ntl];
    vv = fmaxf(vv, __shfl_xor(vv, 16));
    vv = fmaxf(vv, __shfl_xor(vv, 32));
    if (quad == 0) {
      int ch = (wid * 4 + ntl) * 16 + r16;
      atomicMax(&H[b * 256 + ch], __float_as_int(vv));  // vv>=0: int order == float order
    }
  }
}

// ---------- K4: out = H @ fc_w^T + fc_b (one wave per output element) ----------
__global__ __launch_bounds__(64) void fc_kernel(const int* __restrict__ Hi,
                                                const float* __restrict__ fcw,
                                                const float* __restrict__ fcb,
                                                float* __restrict__ out) {
  int b = blockIdx.x / 10, r = blockIdx.x % 10;
  int lane = threadIdx.x;
  const float* Hb = (const float*)Hi + b * 256;
  float s = 0.f;
#pragma unroll
  for (int c = lane; c < 256; c += 64) s += Hb[c] * fcw[r * 256 + c];
#pragma unroll
  for (int m = 32; m > 0; m >>= 1) s += __shfl_xor(s, m);
  if (lane == 0) out[b * 10 + r] = s + fcb[r];
}

// ---------- launch ----------
extern "C" void kernel_launch(void* const* d_in, const int* in_sizes, int n_in,
                              void* d_out, int out_size, void* d_ws, size_t ws_size,
                              hipStream_t stream) {
  const float* x   = (const float*)d_in[0];
  const float* W1  = (const float*)d_in[1];
  const float* W2  = (const float*)d_in[2];
  const float* W3  = (const float*)d_in[3];
  const float* fcw = (const float*)d_in[4];
  const float* fcb = (const float*)d_in[5];
  float* out = (float*)d_out;
  char* ws = (char*)d_ws;

  // workspace layout — p and q are 16*2048*128*2 B = 8,388,608 B EACH
  // (non-overlapping; R6-R8 overlap bug fixed in R9). Total 19,488,768 B.
  float* M2a = (float*)(ws + 0);                          // 1536 B
  float* M2b = (float*)(ws + 2048);                       // 1536 B
  int* H     = (int*)(ws + 8192);                         // 16 KB
  int* idx   = (int*)(ws + 24576);                        // 2,621,440 B
  unsigned short* W3h = (unsigned short*)(ws + 2646016);  // 65,536 B
  unsigned short* p   = (unsigned short*)(ws + 2711552);  // 8,388,608 B
  unsigned short* q   = (unsigned short*)(ws + 11100160); // 8,388,608 B

  prep_kernel<<<32, 128, 0, stream>>>(W1, W2, W3, M2a, M2b, W3h, H);
  pq_kernel<<<BATCH * 64, 64, 0, stream>>>(x, M2a, M2b, p, q);
  knn_kernel<<<BATCH * 128, 256, 0, stream>>>(x, idx);
  gemm_max_kernel<<<BATCH * 96, 256, 0, stream>>>(p, q, idx, W3h, H);
  fc_kernel<<<BATCH * 10, 64, 0, stream>>>(H, fcw, fcb, out);
}